// Round 2
// baseline (13302.814 us; speedup 1.0000x reference)
//
#include <hip/hip_runtime.h>

#define NPTS   8192
#define SCENT  2048
#define KNEIGH 32
#define BATCH  4
#define DFEAT  64

// ---------------------------------------------------------------------------
// Kernel 1: farthest point sampling, float64 (matches numpy f64 reference
// bit-for-bit: same op order, no FMA contraction). One 1024-thread block per
// batch; 8 points/thread resident as doubles; strict '>' argmax with
// first-index tie-break (numpy argmax semantics).
// ---------------------------------------------------------------------------
__global__ __launch_bounds__(1024) void fps_kernel(const float* __restrict__ xyz,
                                                   float* __restrict__ new_xyz,
                                                   int* __restrict__ fps_idx) {
    const int b = blockIdx.x;
    const int t = threadIdx.x;
    const float* X = xyz + (size_t)b * NPTS * 3;

    __shared__ double swv[16];
    __shared__ int    swi[16];
    __shared__ int    swin;
    __shared__ float  sc[3];

    double px[8], py[8], pz[8], dist[8];
#pragma unroll
    for (int j = 0; j < 8; ++j) {
        int p = t * 8 + j;
        px[j] = (double)X[3 * p + 0];
        py[j] = (double)X[3 * p + 1];
        pz[j] = (double)X[3 * p + 2];
        dist[j] = 1e10;
    }
    if (t == 0) { sc[0] = X[0]; sc[1] = X[1]; sc[2] = X[2]; }
    __syncthreads();

    int cur = 0;
#pragma unroll 1
    for (int s = 0; s < SCENT; ++s) {
        if (t == 0) {
            fps_idx[b * SCENT + s] = cur;
            float* o = new_xyz + (size_t)(b * SCENT + s) * 3;
            o[0] = sc[0]; o[1] = sc[1]; o[2] = sc[2];
        }
        const double cx = (double)sc[0], cy = (double)sc[1], cz = (double)sc[2];

        double bv = -1.0;
        int    bi = 0;
#pragma unroll
        for (int j = 0; j < 8; ++j) {
            double dx = __dsub_rn(px[j], cx);
            double dy = __dsub_rn(py[j], cy);
            double dz = __dsub_rn(pz[j], cz);
            double d  = __dadd_rn(__dadd_rn(__dmul_rn(dx, dx), __dmul_rn(dy, dy)),
                                  __dmul_rn(dz, dz));
            double nd = fmin(dist[j], d);
            dist[j] = nd;
            if (nd > bv) { bv = nd; bi = t * 8 + j; }   // strict >: earliest index wins
        }
        // wave reduce (keep-mine-on-tie => lower lane / lower point index wins)
#pragma unroll
        for (int off = 32; off >= 1; off >>= 1) {
            double ov = __shfl_down(bv, off);
            int    oi = __shfl_down(bi, off);
            if (ov > bv) { bv = ov; bi = oi; }
        }
        const int lane = t & 63, w = t >> 6;
        if (lane == 0) { swv[w] = bv; swi[w] = bi; }
        __syncthreads();
        if (t < 64) {
            double v  = (t < 16) ? swv[t] : -1.0;
            int    i2 = (t < 16) ? swi[t] : 0;
#pragma unroll
            for (int off = 8; off >= 1; off >>= 1) {
                double ov = __shfl_down(v, off);
                int    oi = __shfl_down(i2, off);
                if (ov > v) { v = ov; i2 = oi; }
            }
            if (t == 0) swin = i2;
        }
        __syncthreads();
        cur = swin;
        if ((cur >> 3) == t) {
#pragma unroll
            for (int j = 0; j < 8; ++j) {
                if ((cur & 7) == j) {
                    sc[0] = (float)px[j]; sc[1] = (float)py[j]; sc[2] = (float)pz[j];
                }
            }
        }
        __syncthreads();
    }
}

// ---------------------------------------------------------------------------
// Kernel 2: transpose points (B,D,N) -> (B,N,D) for coalesced feature gathers.
// ---------------------------------------------------------------------------
__global__ void transpose_kernel(const float* __restrict__ pts, float* __restrict__ out) {
    __shared__ float tile[32][33];
    const int b  = blockIdx.z;
    const int n0 = blockIdx.x * 32, d0 = blockIdx.y * 32;
    const int tx = threadIdx.x, ty = threadIdx.y;   // block (32,8)
#pragma unroll
    for (int i = 0; i < 4; ++i)
        tile[ty + 8 * i][tx] =
            pts[(size_t)b * DFEAT * NPTS + (size_t)(d0 + ty + 8 * i) * NPTS + n0 + tx];
    __syncthreads();
#pragma unroll
    for (int i = 0; i < 4; ++i)
        out[(size_t)b * NPTS * DFEAT + (size_t)(n0 + ty + 8 * i) * DFEAT + d0 + tx] =
            tile[tx][ty + 8 * i];
}

// ---------------------------------------------------------------------------
// Kernel 3: KNN in float64 (ordering matches numpy f64: (q2+p2)-2*qp, rn ops).
// One thread per query; points staged in LDS chunks; register-resident sorted
// top-32 with stable (first-index) ties like lax.top_k.
// ---------------------------------------------------------------------------
__global__ __launch_bounds__(256, 2) void knn_kernel(const float* __restrict__ xyz,
                                                     const float* __restrict__ new_xyz,
                                                     int* __restrict__ knn_idx) {
    const int b  = blockIdx.y;
    const int t  = threadIdx.x;
    const int qi = blockIdx.x * 256 + t;

    __shared__ float  psx[2048], psy[2048], psz[2048];
    __shared__ double pp2[2048];

    const float* q = new_xyz + (size_t)(b * SCENT + qi) * 3;
    const double qx = (double)q[0], qy = (double)q[1], qz = (double)q[2];
    const double q2 = __dadd_rn(__dadd_rn(__dmul_rn(qx, qx), __dmul_rn(qy, qy)),
                                __dmul_rn(qz, qz));

    double hd[KNEIGH];
    int    hi[KNEIGH];
#pragma unroll
    for (int j = 0; j < KNEIGH; ++j) { hd[j] = 1e300; hi[j] = 0; }

    const float* Xb = xyz + (size_t)b * NPTS * 3;
#pragma unroll 1
    for (int c = 0; c < 4; ++c) {
#pragma unroll
        for (int r = 0; r < 8; ++r) {
            int pl = r * 256 + t;
            int p  = c * 2048 + pl;
            float x = Xb[3 * p + 0], y = Xb[3 * p + 1], z = Xb[3 * p + 2];
            psx[pl] = x; psy[pl] = y; psz[pl] = z;
            double dx = (double)x, dy = (double)y, dz = (double)z;
            pp2[pl] = __dadd_rn(__dadd_rn(__dmul_rn(dx, dx), __dmul_rn(dy, dy)),
                                __dmul_rn(dz, dz));
        }
        __syncthreads();
#pragma unroll 1
        for (int l = 0; l < 2048; ++l) {
            double px = (double)psx[l], py = (double)psy[l], pz = (double)psz[l];
            double qp = __dadd_rn(__dadd_rn(__dmul_rn(qx, px), __dmul_rn(qy, py)),
                                  __dmul_rn(qz, pz));
            double d  = __dsub_rn(__dadd_rn(q2, pp2[l]), __dmul_rn(2.0, qp));
            if (d < hd[KNEIGH - 1]) {      // strict <: boundary ties keep earlier idx
                int idx = c * 2048 + l;
#pragma unroll
                for (int j = KNEIGH - 1; j > 0; --j) {
                    bool   sh   = hd[j - 1] > d;
                    bool   here = hd[j] > d;          // old hd[j]
                    double nv   = sh ? hd[j - 1] : (here ? d : hd[j]);
                    int    ni   = sh ? hi[j - 1] : (here ? idx : hi[j]);
                    hd[j] = nv; hi[j] = ni;
                }
                if (hd[0] > d) { hd[0] = d; hi[0] = idx; }
            }
        }
        __syncthreads();
    }
    int* o = knn_idx + (size_t)(b * SCENT + qi) * KNEIGH;
#pragma unroll
    for (int j = 0; j < KNEIGH; ++j) o[j] = hi[j];
}

// ---------------------------------------------------------------------------
// Kernel 4: gather + 3-layer MLP (BN folded, fp32) + max over K. One thread
// per (b,s,k); weights in LDS (region A: w0-phase then w2-phase).
// ---------------------------------------------------------------------------
__global__ __launch_bounds__(256) void mlp_kernel(
    const float* __restrict__ xyz, const float* __restrict__ new_xyz,
    const float* __restrict__ ptsT, const int* __restrict__ knn_idx,
    const float* __restrict__ w0, const float* __restrict__ g0,
    const float* __restrict__ b0, const float* __restrict__ m0,
    const float* __restrict__ v0, const float* __restrict__ w1,
    const float* __restrict__ g1, const float* __restrict__ b1,
    const float* __restrict__ m1, const float* __restrict__ v1,
    const float* __restrict__ w2, const float* __restrict__ g2,
    const float* __restrict__ b2, const float* __restrict__ m2,
    const float* __restrict__ v2, float* __restrict__ out_points) {

    __shared__ float regA[8192];   // w0 padded/permuted (64x68), later w2 (128x64)
    __shared__ float regB[4096];   // w1 (64x64)
    __shared__ float prm[512];     // a0,c0,a1,c1 (64 each) | a2,c2 (128 each)

    const int t = threadIdx.x;
    if (t < 64) {
        float a0v = g0[t] / sqrtf(v0[t] + 1e-5f);
        prm[t]       = a0v;
        prm[64 + t]  = b0[t] - m0[t] * a0v;
        float a1v = g1[t] / sqrtf(v1[t] + 1e-5f);
        prm[128 + t] = a1v;
        prm[192 + t] = b1[t] - m1[t] * a1v;
    } else if (t < 192) {
        int o = t - 64;
        float a2v = g2[o] / sqrtf(v2[o] + 1e-5f);
        prm[256 + o] = a2v;
        prm[384 + o] = b2[o] - m2[o] * a2v;
    }
    for (int idx = t; idx < 64 * 68; idx += 256) {
        int o = idx / 68, i = idx - o * 68;
        float v;
        if (i < 64)      v = w0[o * 67 + 3 + i];     // feature cols first
        else if (i < 67) v = w0[o * 67 + (i - 64)];  // xyz cols
        else             v = 0.0f;                   // pad
        regA[idx] = v;
    }
    for (int idx = t; idx < 64 * 64; idx += 256) regB[idx] = w1[idx];
    __syncthreads();

    const int gid = blockIdx.x * 256 + t;
    const int sl  = gid >> 5;               // (b,s) linear; k = gid & 31
    const int s   = sl & (SCENT - 1);
    const int b   = sl >> 11;
    const int nidx = knn_idx[gid];

    const float* q  = new_xyz + (size_t)(b * SCENT + s) * 3;
    const float* P3 = xyz + (size_t)(b * NPTS + nidx) * 3;
    const float dx = P3[0] - q[0], dy = P3[1] - q[1], dz = P3[2] - q[2];

    const float4* F = (const float4*)(ptsT + ((size_t)b * NPTS + nidx) * 64);
    float4 xv[17];
#pragma unroll
    for (int i = 0; i < 16; ++i) xv[i] = F[i];
    xv[16] = make_float4(dx, dy, dz, 0.0f);

    float h0[64];
    const float4* W0 = (const float4*)regA;
#pragma unroll
    for (int o = 0; o < 64; ++o) {
        float acc = 0.f;
#pragma unroll
        for (int i = 0; i < 17; ++i) {
            float4 w = W0[o * 17 + i];
            acc = fmaf(xv[i].x, w.x, acc);
            acc = fmaf(xv[i].y, w.y, acc);
            acc = fmaf(xv[i].z, w.z, acc);
            acc = fmaf(xv[i].w, w.w, acc);
        }
        h0[o] = fmaxf(fmaf(acc, prm[o], prm[64 + o]), 0.f);
    }
    __syncthreads();                                 // done reading w0
    for (int idx = t; idx < 128 * 64; idx += 256) regA[idx] = w2[idx];
    __syncthreads();

    float h1[64];
    const float4* W1 = (const float4*)regB;
#pragma unroll
    for (int o = 0; o < 64; ++o) {
        float acc = 0.f;
#pragma unroll
        for (int i = 0; i < 16; ++i) {
            float4 w = W1[o * 16 + i];
            acc = fmaf(h0[4 * i + 0], w.x, acc);
            acc = fmaf(h0[4 * i + 1], w.y, acc);
            acc = fmaf(h0[4 * i + 2], w.z, acc);
            acc = fmaf(h0[4 * i + 3], w.w, acc);
        }
        h1[o] = fmaxf(fmaf(acc, prm[128 + o], prm[192 + o]), 0.f);
    }

    const float4* W2 = (const float4*)regA;
    float* outp = out_points + (size_t)b * 128 * SCENT + s;
    const int lane = t & 63;
#pragma unroll 1
    for (int o = 0; o < 128; ++o) {
        float acc = 0.f;
#pragma unroll
        for (int i = 0; i < 16; ++i) {
            float4 w = W2[o * 16 + i];
            acc = fmaf(h1[4 * i + 0], w.x, acc);
            acc = fmaf(h1[4 * i + 1], w.y, acc);
            acc = fmaf(h1[4 * i + 2], w.z, acc);
            acc = fmaf(h1[4 * i + 3], w.w, acc);
        }
        float y = fmaxf(fmaf(acc, prm[256 + o], prm[384 + o]), 0.f);
#pragma unroll
        for (int off = 16; off >= 1; off >>= 1) y = fmaxf(y, __shfl_xor(y, off));
        if ((lane & 31) == 0) outp[(size_t)o * SCENT] = y;
    }
}

// ---------------------------------------------------------------------------
extern "C" void kernel_launch(void* const* d_in, const int* in_sizes, int n_in,
                              void* d_out, int out_size, void* d_ws, size_t ws_size,
                              hipStream_t stream) {
    const float* xyz    = (const float*)d_in[0];
    const float* points = (const float*)d_in[1];
    const float* w0 = (const float*)d_in[2];
    const float* g0 = (const float*)d_in[3];
    const float* b0 = (const float*)d_in[4];
    const float* m0 = (const float*)d_in[5];
    const float* v0 = (const float*)d_in[6];
    const float* w1 = (const float*)d_in[7];
    const float* g1 = (const float*)d_in[8];
    const float* b1 = (const float*)d_in[9];
    const float* m1 = (const float*)d_in[10];
    const float* v1 = (const float*)d_in[11];
    const float* w2 = (const float*)d_in[12];
    const float* g2 = (const float*)d_in[13];
    const float* b2 = (const float*)d_in[14];
    const float* m2 = (const float*)d_in[15];
    const float* v2 = (const float*)d_in[16];

    float* out_xyz    = (float*)d_out;                               // (B,S,3)
    float* out_points = (float*)d_out + (size_t)BATCH * SCENT * 3;   // (B,128,S)

    char* ws = (char*)d_ws;
    int*   fps_idx = (int*)ws;                                   // 32 KB
    int*   knn_idx = (int*)(ws + 32768);                         // 1 MB
    float* ptsT    = (float*)(ws + 32768 + (size_t)BATCH * SCENT * KNEIGH * 4); // 8 MB

    fps_kernel<<<BATCH, 1024, 0, stream>>>(xyz, out_xyz, fps_idx);
    transpose_kernel<<<dim3(NPTS / 32, DFEAT / 32, BATCH), dim3(32, 8), 0, stream>>>(points, ptsT);
    knn_kernel<<<dim3(SCENT / 256, BATCH), 256, 0, stream>>>(xyz, out_xyz, knn_idx);
    mlp_kernel<<<(BATCH * SCENT * KNEIGH) / 256, 256, 0, stream>>>(
        xyz, out_xyz, ptsT, knn_idx,
        w0, g0, b0, m0, v0, w1, g1, b1, m1, v1, w2, g2, b2, m2, v2, out_points);
}

// Round 3
// 3338.620 us; speedup vs baseline: 3.9845x; 3.9845x over previous
//
#include <hip/hip_runtime.h>
#include <cfloat>

#define NPTS   8192
#define SCENT  2048
#define KNEIGH 32
#define BATCH  4
#define DFEAT  64

// ---------------------------------------------------------------------------
// Kernel 1: FPS, float64-exact (numpy op order, no FMA). One 512-thread block
// per batch; 16 points/thread resident in f64 REGISTERS (no spill: 512thr ->
// 2 waves/SIMD -> 256-VGPR cap). Single barrier per iteration via
// double-buffered reduce slots; centroid re-read from global (L1 broadcast).
// ---------------------------------------------------------------------------
__global__ __launch_bounds__(512, 2) void fps_kernel(const float* __restrict__ xyz,
                                                     float* __restrict__ new_xyz,
                                                     int* __restrict__ fps_idx) {
    const int b = blockIdx.x;
    const int t = threadIdx.x;
    const float* X = xyz + (size_t)b * NPTS * 3;

    __shared__ double swv[2][8];
    __shared__ int    swi[2][8];

    double px[16], py[16], pz[16], dist[16];
#pragma unroll
    for (int j = 0; j < 16; ++j) {
        int p = t * 16 + j;
        px[j] = (double)X[3 * p + 0];
        py[j] = (double)X[3 * p + 1];
        pz[j] = (double)X[3 * p + 2];
        dist[j] = (double)1e10f;
    }
    int   cur = 0;
    float fcx = X[0], fcy = X[1], fcz = X[2];
    int   buf = 0;
    const int lane = t & 63, w = t >> 6;

#pragma unroll 1
    for (int s = 0; s < SCENT; ++s) {
        if (t == 0) {
            fps_idx[b * SCENT + s] = cur;
            float* o = new_xyz + (size_t)(b * SCENT + s) * 3;
            o[0] = fcx; o[1] = fcy; o[2] = fcz;
        }
        const double cx = (double)fcx, cy = (double)fcy, cz = (double)fcz;

        double bv = -1.0; int bi = 0;
#pragma unroll
        for (int j = 0; j < 16; ++j) {
            double dx = __dsub_rn(px[j], cx);
            double dy = __dsub_rn(py[j], cy);
            double dz = __dsub_rn(pz[j], cz);
            double d  = __dadd_rn(__dadd_rn(__dmul_rn(dx, dx), __dmul_rn(dy, dy)),
                                  __dmul_rn(dz, dz));
            double nd = fmin(dist[j], d);
            dist[j] = nd;
            if (nd > bv) { bv = nd; bi = t * 16 + j; }   // strict >: earliest idx wins
        }
        // wave reduce (keep-mine-on-tie => lower lane = lower point index wins)
#pragma unroll
        for (int off = 32; off >= 1; off >>= 1) {
            double ov = __shfl_down(bv, off);
            int    oi = __shfl_down(bi, off);
            if (ov > bv) { bv = ov; bi = oi; }
        }
        if (lane == 0) { swv[buf][w] = bv; swi[buf][w] = bi; }
        __syncthreads();
        // every thread redundantly reduces the 8 wave-bests (LDS broadcast reads)
        double mv = swv[buf][0]; int mi = swi[buf][0];
#pragma unroll
        for (int w2 = 1; w2 < 8; ++w2) {
            double v = swv[buf][w2];
            if (v > mv) { mv = v; mi = swi[buf][w2]; }   // strict >: earlier wave wins
        }
        cur = mi; buf ^= 1;
        const float* cp = X + 3 * (size_t)cur;           // same addr all lanes: broadcast
        fcx = cp[0]; fcy = cp[1]; fcz = cp[2];
    }
}

// ---------------------------------------------------------------------------
// Kernel 2: transpose points (B,D,N) -> (B,N,D).
// ---------------------------------------------------------------------------
__global__ void transpose_kernel(const float* __restrict__ pts, float* __restrict__ out) {
    __shared__ float tile[32][33];
    const int b  = blockIdx.z;
    const int n0 = blockIdx.x * 32, d0 = blockIdx.y * 32;
    const int tx = threadIdx.x, ty = threadIdx.y;   // block (32,8)
#pragma unroll
    for (int i = 0; i < 4; ++i)
        tile[ty + 8 * i][tx] =
            pts[(size_t)b * DFEAT * NPTS + (size_t)(d0 + ty + 8 * i) * NPTS + n0 + tx];
    __syncthreads();
#pragma unroll
    for (int i = 0; i < 4; ++i)
        out[(size_t)b * NPTS * DFEAT + (size_t)(n0 + ty + 8 * i) * DFEAT + d0 + tx] =
            tile[tx][ty + 8 * i];
}

// ---------------------------------------------------------------------------
// Kernel 3: KNN, one WAVE per query. f64 ordering identical to numpy:
// d = (q2 + p2) - 2*qp, rn ops, lexicographic (d, idx) ties. Sorted top-32
// lives in lanes 0..31; candidates found by ballot vs running threshold tau
// (= entry 31); each insert is a wave-parallel shfl_up shift (~12 instr).
// ---------------------------------------------------------------------------
__global__ __launch_bounds__(256) void knn_kernel(const float* __restrict__ xyz,
                                                  const float* __restrict__ new_xyz,
                                                  int* __restrict__ knn_idx) {
    const int b    = blockIdx.y;
    const int wid  = threadIdx.x >> 6;
    const int lane = threadIdx.x & 63;
    const int qi   = blockIdx.x * 4 + wid;

    __shared__ float4 sp[2048];   // x,y,z,- per point (chunk)
    __shared__ double sp2[2048];  // f64 |p|^2 per point (chunk)

    const float* q = new_xyz + (size_t)(b * SCENT + qi) * 3;
    const double qx = (double)q[0], qy = (double)q[1], qz = (double)q[2];
    const double q2 = __dadd_rn(__dadd_rn(__dmul_rn(qx, qx), __dmul_rn(qy, qy)),
                                __dmul_rn(qz, qz));

    double ld   = DBL_MAX;        // list entry (lanes 0..31); lanes 32..63 inert
    int    li   = 0x7fffffff;
    double taud = DBL_MAX;        // current 32nd-smallest (lex) = entry 31
    int    taui = 0x7fffffff;

    const float* Xb = xyz + (size_t)b * NPTS * 3;
#pragma unroll 1
    for (int c = 0; c < 4; ++c) {
        __syncthreads();          // protect prior chunk's readers
#pragma unroll
        for (int r = 0; r < 8; ++r) {
            int pl = r * 256 + threadIdx.x;
            int p  = c * 2048 + pl;
            float x = Xb[3 * p + 0], y = Xb[3 * p + 1], z = Xb[3 * p + 2];
            sp[pl] = make_float4(x, y, z, 0.0f);
            double dx = (double)x, dy = (double)y, dz = (double)z;
            sp2[pl] = __dadd_rn(__dadd_rn(__dmul_rn(dx, dx), __dmul_rn(dy, dy)),
                                __dmul_rn(dz, dz));
        }
        __syncthreads();
#pragma unroll 1
        for (int i = 0; i < 32; ++i) {
            const int pl   = i * 64 + lane;
            const int pidx = c * 2048 + pl;
            float4 P = sp[pl];
            double px = (double)P.x, py = (double)P.y, pz = (double)P.z;
            double qp = __dadd_rn(__dadd_rn(__dmul_rn(qx, px), __dmul_rn(qy, py)),
                                  __dmul_rn(qz, pz));
            double d  = __dsub_rn(__dadd_rn(q2, sp2[pl]), __dmul_rn(2.0, qp));
            bool cand = (d < taud) || (d == taud && pidx < taui);
            unsigned long long m = __ballot(cand);
            while (m) {
                int s = __ffsll((unsigned long long)m) - 1;
                m &= m - 1;
                double dv = __shfl(d, s);
                int    iv = __shfl(pidx, s);
                if (dv < taud || (dv == taud && iv < taui)) {   // re-check vs tightened tau
                    bool gt = (lane < 32) && (ld > dv || (ld == dv && li > iv));
                    unsigned long long gm = __ballot(gt);
                    double ud = __shfl_up(ld, 1);
                    int    ui = __shfl_up(li, 1);
                    if (gt) { ld = ud; li = ui; }
                    bool first = gt && ((lane == 0) || !((gm >> (lane - 1)) & 1ull));
                    if (first) { ld = dv; li = iv; }
                    taud = __shfl(ld, 31);
                    taui = __shfl(li, 31);
                }
            }
        }
    }
    if (lane < 32) knn_idx[(size_t)(b * SCENT + qi) * KNEIGH + lane] = li;
}

// ---------------------------------------------------------------------------
// Kernel 4: gather + 3-layer MLP (BN folded, fp32) + max over K. One thread
// per (b,s,k); weights in LDS (region A: w0-phase then w2-phase).
// ---------------------------------------------------------------------------
__global__ __launch_bounds__(256) void mlp_kernel(
    const float* __restrict__ xyz, const float* __restrict__ new_xyz,
    const float* __restrict__ ptsT, const int* __restrict__ knn_idx,
    const float* __restrict__ w0, const float* __restrict__ g0,
    const float* __restrict__ b0, const float* __restrict__ m0,
    const float* __restrict__ v0, const float* __restrict__ w1,
    const float* __restrict__ g1, const float* __restrict__ b1,
    const float* __restrict__ m1, const float* __restrict__ v1,
    const float* __restrict__ w2, const float* __restrict__ g2,
    const float* __restrict__ b2, const float* __restrict__ m2,
    const float* __restrict__ v2, float* __restrict__ out_points) {

    __shared__ float regA[8192];   // w0 padded/permuted (64x68), later w2 (128x64)
    __shared__ float regB[4096];   // w1 (64x64)
    __shared__ float prm[512];     // a0,c0,a1,c1 (64 each) | a2,c2 (128 each)

    const int t = threadIdx.x;
    if (t < 64) {
        float a0v = g0[t] / sqrtf(v0[t] + 1e-5f);
        prm[t]       = a0v;
        prm[64 + t]  = b0[t] - m0[t] * a0v;
        float a1v = g1[t] / sqrtf(v1[t] + 1e-5f);
        prm[128 + t] = a1v;
        prm[192 + t] = b1[t] - m1[t] * a1v;
    } else if (t < 192) {
        int o = t - 64;
        float a2v = g2[o] / sqrtf(v2[o] + 1e-5f);
        prm[256 + o] = a2v;
        prm[384 + o] = b2[o] - m2[o] * a2v;
    }
    for (int idx = t; idx < 64 * 68; idx += 256) {
        int o = idx / 68, i = idx - o * 68;
        float v;
        if (i < 64)      v = w0[o * 67 + 3 + i];     // feature cols first
        else if (i < 67) v = w0[o * 67 + (i - 64)];  // xyz cols
        else             v = 0.0f;                   // pad
        regA[idx] = v;
    }
    for (int idx = t; idx < 64 * 64; idx += 256) regB[idx] = w1[idx];
    __syncthreads();

    const int gid = blockIdx.x * 256 + t;
    const int sl  = gid >> 5;               // (b,s) linear; k = gid & 31
    const int s   = sl & (SCENT - 1);
    const int b   = sl >> 11;
    const int nidx = knn_idx[gid];

    const float* q  = new_xyz + (size_t)(b * SCENT + s) * 3;
    const float* P3 = xyz + (size_t)(b * NPTS + nidx) * 3;
    const float dx = P3[0] - q[0], dy = P3[1] - q[1], dz = P3[2] - q[2];

    const float4* F = (const float4*)(ptsT + ((size_t)b * NPTS + nidx) * 64);
    float4 xv[17];
#pragma unroll
    for (int i = 0; i < 16; ++i) xv[i] = F[i];
    xv[16] = make_float4(dx, dy, dz, 0.0f);

    float h0[64];
    const float4* W0 = (const float4*)regA;
#pragma unroll
    for (int o = 0; o < 64; ++o) {
        float acc = 0.f;
#pragma unroll
        for (int i = 0; i < 17; ++i) {
            float4 w = W0[o * 17 + i];
            acc = fmaf(xv[i].x, w.x, acc);
            acc = fmaf(xv[i].y, w.y, acc);
            acc = fmaf(xv[i].z, w.z, acc);
            acc = fmaf(xv[i].w, w.w, acc);
        }
        h0[o] = fmaxf(fmaf(acc, prm[o], prm[64 + o]), 0.f);
    }
    __syncthreads();                                 // done reading w0
    for (int idx = t; idx < 128 * 64; idx += 256) regA[idx] = w2[idx];
    __syncthreads();

    float h1[64];
    const float4* W1 = (const float4*)regB;
#pragma unroll
    for (int o = 0; o < 64; ++o) {
        float acc = 0.f;
#pragma unroll
        for (int i = 0; i < 16; ++i) {
            float4 w = W1[o * 16 + i];
            acc = fmaf(h0[4 * i + 0], w.x, acc);
            acc = fmaf(h0[4 * i + 1], w.y, acc);
            acc = fmaf(h0[4 * i + 2], w.z, acc);
            acc = fmaf(h0[4 * i + 3], w.w, acc);
        }
        h1[o] = fmaxf(fmaf(acc, prm[128 + o], prm[192 + o]), 0.f);
    }

    const float4* W2 = (const float4*)regA;
    float* outp = out_points + (size_t)b * 128 * SCENT + s;
    const int lane = t & 63;
#pragma unroll 1
    for (int o = 0; o < 128; ++o) {
        float acc = 0.f;
#pragma unroll
        for (int i = 0; i < 16; ++i) {
            float4 w = W2[o * 16 + i];
            acc = fmaf(h1[4 * i + 0], w.x, acc);
            acc = fmaf(h1[4 * i + 1], w.y, acc);
            acc = fmaf(h1[4 * i + 2], w.z, acc);
            acc = fmaf(h1[4 * i + 3], w.w, acc);
        }
        float y = fmaxf(fmaf(acc, prm[256 + o], prm[384 + o]), 0.f);
#pragma unroll
        for (int off = 16; off >= 1; off >>= 1) y = fmaxf(y, __shfl_xor(y, off));
        if ((lane & 31) == 0) outp[(size_t)o * SCENT] = y;
    }
}

// ---------------------------------------------------------------------------
extern "C" void kernel_launch(void* const* d_in, const int* in_sizes, int n_in,
                              void* d_out, int out_size, void* d_ws, size_t ws_size,
                              hipStream_t stream) {
    const float* xyz    = (const float*)d_in[0];
    const float* points = (const float*)d_in[1];
    const float* w0 = (const float*)d_in[2];
    const float* g0 = (const float*)d_in[3];
    const float* b0 = (const float*)d_in[4];
    const float* m0 = (const float*)d_in[5];
    const float* v0 = (const float*)d_in[6];
    const float* w1 = (const float*)d_in[7];
    const float* g1 = (const float*)d_in[8];
    const float* b1 = (const float*)d_in[9];
    const float* m1 = (const float*)d_in[10];
    const float* v1 = (const float*)d_in[11];
    const float* w2 = (const float*)d_in[12];
    const float* g2 = (const float*)d_in[13];
    const float* b2 = (const float*)d_in[14];
    const float* m2 = (const float*)d_in[15];
    const float* v2 = (const float*)d_in[16];

    float* out_xyz    = (float*)d_out;                               // (B,S,3)
    float* out_points = (float*)d_out + (size_t)BATCH * SCENT * 3;   // (B,128,S)

    char* ws = (char*)d_ws;
    int*   fps_idx = (int*)ws;                                   // 32 KB
    int*   knn_idx = (int*)(ws + 32768);                         // 1 MB
    float* ptsT    = (float*)(ws + 32768 + (size_t)BATCH * SCENT * KNEIGH * 4); // 8 MB

    fps_kernel<<<BATCH, 512, 0, stream>>>(xyz, out_xyz, fps_idx);
    transpose_kernel<<<dim3(NPTS / 32, DFEAT / 32, BATCH), dim3(32, 8), 0, stream>>>(points, ptsT);
    knn_kernel<<<dim3(SCENT / 4, BATCH), 256, 0, stream>>>(xyz, out_xyz, knn_idx);
    mlp_kernel<<<(BATCH * SCENT * KNEIGH) / 256, 256, 0, stream>>>(
        xyz, out_xyz, ptsT, knn_idx,
        w0, g0, b0, m0, v0, w1, g1, b1, m1, v1, w2, g2, b2, m2, v2, out_points);
}

// Round 4
// 3156.758 us; speedup vs baseline: 4.2141x; 1.0576x over previous
//
#include <hip/hip_runtime.h>
#include <cfloat>
#include <climits>

#define NPTS   8192
#define SCENT  2048
#define KNEIGH 32
#define BATCH  4
#define DFEAT  64
#define FPS_T  256     // threads in fps block
#define PPT    32      // points per thread (stride-FPS_T ownership)
#define CAP    64      // fallback candidate list capacity

// ---------------------------------------------------------------------------
// Kernel 1: FPS. f32 fast path + exact-f64 fallback.
// Exactness argument: d32 (any fma contraction) satisfies |d32-d64| <= 5u*d,
// u=2^-24; running mins preserve the relative bound. If the top-2 f32 dists
// are separated by > 2e-6 relative (>> 13u), the f32 argmax equals the f64
// argmax. Otherwise all points with dist32 >= v1*(1-2e-6) (provably includes
// the f64 winner) are re-scored exactly in f64 against the full centroid
// history with lexicographic (d, idx) ordering = numpy argmax tie rule.
// One 256-thread block per batch; 32 f32 pts/thread in registers; xyz in LDS.
// ---------------------------------------------------------------------------
__global__ __launch_bounds__(FPS_T, 1) void fps_kernel(const float* __restrict__ xyz,
                                                       float* __restrict__ new_xyz,
                                                       int* __restrict__ fps_idx) {
    const int b = blockIdx.x, t = threadIdx.x;
    const int lane = t & 63, w = t >> 6;
    const float* X = xyz + (size_t)b * NPTS * 3;

    __shared__ float  sx[NPTS], sy[NPTS], sz[NPTS];   // 96 KB point table
    __shared__ int    shist[SCENT];                   // selected centroid indices
    __shared__ float  swv1[2][4], swv2[2][4];
    __shared__ int    swi1[2][4];
    __shared__ double sdd[2][4];
    __shared__ double sfv[2][4];
    __shared__ int    sfi[2][4];
    __shared__ int    scnt;
    __shared__ int    scand[CAP];

    for (int p = t; p < NPTS; p += FPS_T) {
        sx[p] = X[3 * p + 0]; sy[p] = X[3 * p + 1]; sz[p] = X[3 * p + 2];
    }
    __syncthreads();

    float px[PPT], py[PPT], pz[PPT], dist[PPT];
#pragma unroll
    for (int j = 0; j < PPT; ++j) {
        int p = t + FPS_T * j;                 // stride ownership: LDS conflict-free
        px[j] = sx[p]; py[j] = sy[p]; pz[j] = sz[p];
        dist[j] = 1e10f;
    }

    int cur = 0, buf = 0;
#pragma unroll 1
    for (int s = 0; s < SCENT; ++s) {
        if (t == 0) {
            fps_idx[b * SCENT + s] = cur;
            float* o = new_xyz + (size_t)(b * SCENT + s) * 3;
            o[0] = sx[cur]; o[1] = sy[cur]; o[2] = sz[cur];
            shist[s] = cur;
        }
        const float cx = sx[cur], cy = sy[cur], cz = sz[cur];

        float v1 = -1.0f, v2 = -1.0f; int i1 = 0;
#pragma unroll
        for (int j = 0; j < PPT; ++j) {
            float dx = px[j] - cx, dy = py[j] - cy, dz = pz[j] - cz;
            float d  = dx * dx + dy * dy + dz * dz;
            float nd = fminf(dist[j], d);
            dist[j] = nd;
            bool g = nd > v1;
            v2 = fmaxf(v2, fminf(v1, nd));     // second-max tracking
            v1 = fmaxf(v1, nd);
            i1 = g ? (t + FPS_T * j) : i1;
        }
        // wave top-2 reduce
#pragma unroll
        for (int off = 32; off >= 1; off >>= 1) {
            float ov1 = __shfl_down(v1, off);
            float ov2 = __shfl_down(v2, off);
            int   oi1 = __shfl_down(i1, off);
            float lo  = fminf(v1, ov1);
            bool  tk  = ov1 > v1;
            v1 = fmaxf(v1, ov1);
            i1 = tk ? oi1 : i1;
            v2 = fmaxf(fmaxf(v2, ov2), lo);
        }
        if (lane == 0) { swv1[buf][w] = v1; swv2[buf][w] = v2; swi1[buf][w] = i1; }
        __syncthreads();
        // redundant 4-slot merge (identical on every thread -> uniform result)
        v1 = swv1[buf][0]; v2 = swv2[buf][0]; i1 = swi1[buf][0];
#pragma unroll
        for (int w2 = 1; w2 < 4; ++w2) {
            float ov1 = swv1[buf][w2], ov2 = swv2[buf][w2];
            int   oi1 = swi1[buf][w2];
            float lo  = fminf(v1, ov1);
            bool  tk  = ov1 > v1;
            v1 = fmaxf(v1, ov1);
            i1 = tk ? oi1 : i1;
            v2 = fmaxf(fmaxf(v2, ov2), lo);
        }

        const float thresh = __fmul_rn(v1, 0.999998f);   // v1*(1-2e-6)
        if (v2 >= thresh) {
            // ---- exact-f64 fallback (rare; block-uniform branch) ----
            if (t == 0) scnt = 0;
            __syncthreads();
#pragma unroll
            for (int j = 0; j < PPT; ++j) {
                if (dist[j] >= thresh) {
                    int slot = atomicAdd(&scnt, 1);
                    if (slot < CAP) scand[slot] = t + FPS_T * j;
                }
            }
            __syncthreads();
            const int m = scnt;
            if (m <= CAP) {
                double bd = -1.0; int bi = INT_MAX;
#pragma unroll 1
                for (int k = 0; k < m; ++k) {
                    const int pidx = scand[k];
                    const double pxd = (double)sx[pidx], pyd = (double)sy[pidx],
                                 pzd = (double)sz[pidx];
                    double dd = 1e10;
                    for (int i = t; i <= s; i += FPS_T) {
                        int h = shist[i];
                        double dx = __dsub_rn(pxd, (double)sx[h]);
                        double dy = __dsub_rn(pyd, (double)sy[h]);
                        double dz = __dsub_rn(pzd, (double)sz[h]);
                        double d  = __dadd_rn(__dadd_rn(__dmul_rn(dx, dx), __dmul_rn(dy, dy)),
                                              __dmul_rn(dz, dz));
                        dd = fmin(dd, d);
                    }
#pragma unroll
                    for (int off = 32; off >= 1; off >>= 1)
                        dd = fmin(dd, __shfl_down(dd, off));
                    if (lane == 0) sdd[k & 1][w] = dd;
                    __syncthreads();
                    double ddm = fmin(fmin(sdd[k & 1][0], sdd[k & 1][1]),
                                      fmin(sdd[k & 1][2], sdd[k & 1][3]));
                    if (ddm > bd || (ddm == bd && pidx < bi)) { bd = ddm; bi = pidx; }
                }
                cur = bi;
            } else {
                // ultimate safety net: exact scan of all points (never on random data)
                double bv = -1.0; int bi = INT_MAX;
#pragma unroll 1
                for (int j = 0; j < PPT; ++j) {
                    const double pxd = (double)px[j], pyd = (double)py[j],
                                 pzd = (double)pz[j];
                    double dd = 1e10;
                    for (int i = 0; i <= s; ++i) {
                        int h = shist[i];
                        double dx = __dsub_rn(pxd, (double)sx[h]);
                        double dy = __dsub_rn(pyd, (double)sy[h]);
                        double dz = __dsub_rn(pzd, (double)sz[h]);
                        double d  = __dadd_rn(__dadd_rn(__dmul_rn(dx, dx), __dmul_rn(dy, dy)),
                                              __dmul_rn(dz, dz));
                        dd = fmin(dd, d);
                    }
                    int pidx = t + FPS_T * j;
                    if (dd > bv || (dd == bv && pidx < bi)) { bv = dd; bi = pidx; }
                }
#pragma unroll
                for (int off = 32; off >= 1; off >>= 1) {
                    double ov = __shfl_down(bv, off);
                    int    oi = __shfl_down(bi, off);
                    if (ov > bv || (ov == bv && oi < bi)) { bv = ov; bi = oi; }
                }
                if (lane == 0) { sfv[buf][w] = bv; sfi[buf][w] = bi; }
                __syncthreads();
                bv = sfv[buf][0]; bi = sfi[buf][0];
#pragma unroll
                for (int w2 = 1; w2 < 4; ++w2) {
                    double ov = sfv[buf][w2]; int oi = sfi[buf][w2];
                    if (ov > bv || (ov == bv && oi < bi)) { bv = ov; bi = oi; }
                }
                cur = bi;
            }
        } else {
            cur = i1;                       // provably the unique f64 argmax
        }
        buf ^= 1;
    }
}

// ---------------------------------------------------------------------------
// Kernel 2: transpose points (B,D,N) -> (B,N,D).
// ---------------------------------------------------------------------------
__global__ void transpose_kernel(const float* __restrict__ pts, float* __restrict__ out) {
    __shared__ float tile[32][33];
    const int b  = blockIdx.z;
    const int n0 = blockIdx.x * 32, d0 = blockIdx.y * 32;
    const int tx = threadIdx.x, ty = threadIdx.y;   // block (32,8)
#pragma unroll
    for (int i = 0; i < 4; ++i)
        tile[ty + 8 * i][tx] =
            pts[(size_t)b * DFEAT * NPTS + (size_t)(d0 + ty + 8 * i) * NPTS + n0 + tx];
    __syncthreads();
#pragma unroll
    for (int i = 0; i < 4; ++i)
        out[(size_t)b * NPTS * DFEAT + (size_t)(n0 + ty + 8 * i) * DFEAT + d0 + tx] =
            tile[tx][ty + 8 * i];
}

// ---------------------------------------------------------------------------
// Kernel 3: KNN, one WAVE per query. f64 ordering identical to numpy:
// d = (q2 + p2) - 2*qp, rn ops, lexicographic (d, idx) ties. Sorted top-32
// lives in lanes 0..31; candidates found by ballot vs running threshold tau
// (= entry 31); each insert is a wave-parallel shfl_up shift.
// ---------------------------------------------------------------------------
__global__ __launch_bounds__(256) void knn_kernel(const float* __restrict__ xyz,
                                                  const float* __restrict__ new_xyz,
                                                  int* __restrict__ knn_idx) {
    const int b    = blockIdx.y;
    const int wid  = threadIdx.x >> 6;
    const int lane = threadIdx.x & 63;
    const int qi   = blockIdx.x * 4 + wid;

    __shared__ float4 sp[2048];
    __shared__ double sp2[2048];

    const float* q = new_xyz + (size_t)(b * SCENT + qi) * 3;
    const double qx = (double)q[0], qy = (double)q[1], qz = (double)q[2];
    const double q2 = __dadd_rn(__dadd_rn(__dmul_rn(qx, qx), __dmul_rn(qy, qy)),
                                __dmul_rn(qz, qz));

    double ld   = DBL_MAX;
    int    li   = 0x7fffffff;
    double taud = DBL_MAX;
    int    taui = 0x7fffffff;

    const float* Xb = xyz + (size_t)b * NPTS * 3;
#pragma unroll 1
    for (int c = 0; c < 4; ++c) {
        __syncthreads();
#pragma unroll
        for (int r = 0; r < 8; ++r) {
            int pl = r * 256 + threadIdx.x;
            int p  = c * 2048 + pl;
            float x = Xb[3 * p + 0], y = Xb[3 * p + 1], z = Xb[3 * p + 2];
            sp[pl] = make_float4(x, y, z, 0.0f);
            double dx = (double)x, dy = (double)y, dz = (double)z;
            sp2[pl] = __dadd_rn(__dadd_rn(__dmul_rn(dx, dx), __dmul_rn(dy, dy)),
                                __dmul_rn(dz, dz));
        }
        __syncthreads();
#pragma unroll 1
        for (int i = 0; i < 32; ++i) {
            const int pl   = i * 64 + lane;
            const int pidx = c * 2048 + pl;
            float4 P = sp[pl];
            double px = (double)P.x, py = (double)P.y, pz = (double)P.z;
            double qp = __dadd_rn(__dadd_rn(__dmul_rn(qx, px), __dmul_rn(qy, py)),
                                  __dmul_rn(qz, pz));
            double d  = __dsub_rn(__dadd_rn(q2, sp2[pl]), __dmul_rn(2.0, qp));
            bool cand = (d < taud) || (d == taud && pidx < taui);
            unsigned long long m = __ballot(cand);
            while (m) {
                int sl = __ffsll((unsigned long long)m) - 1;
                m &= m - 1;
                double dv = __shfl(d, sl);
                int    iv = __shfl(pidx, sl);
                if (dv < taud || (dv == taud && iv < taui)) {
                    bool gt = (lane < 32) && (ld > dv || (ld == dv && li > iv));
                    unsigned long long gm = __ballot(gt);
                    double ud = __shfl_up(ld, 1);
                    int    ui = __shfl_up(li, 1);
                    if (gt) { ld = ud; li = ui; }
                    bool first = gt && ((lane == 0) || !((gm >> (lane - 1)) & 1ull));
                    if (first) { ld = dv; li = iv; }
                    taud = __shfl(ld, 31);
                    taui = __shfl(li, 31);
                }
            }
        }
    }
    if (lane < 32) knn_idx[(size_t)(b * SCENT + qi) * KNEIGH + lane] = li;
}

// ---------------------------------------------------------------------------
// Kernel 4: gather + 3-layer MLP (BN folded, fp32) + max over K. One thread
// per (b,s,k); weights in LDS (region A: w0-phase then w2-phase).
// ---------------------------------------------------------------------------
__global__ __launch_bounds__(256) void mlp_kernel(
    const float* __restrict__ xyz, const float* __restrict__ new_xyz,
    const float* __restrict__ ptsT, const int* __restrict__ knn_idx,
    const float* __restrict__ w0, const float* __restrict__ g0,
    const float* __restrict__ b0, const float* __restrict__ m0,
    const float* __restrict__ v0, const float* __restrict__ w1,
    const float* __restrict__ g1, const float* __restrict__ b1,
    const float* __restrict__ m1, const float* __restrict__ v1,
    const float* __restrict__ w2, const float* __restrict__ g2,
    const float* __restrict__ b2, const float* __restrict__ m2,
    const float* __restrict__ v2, float* __restrict__ out_points) {

    __shared__ float regA[8192];   // w0 padded/permuted (64x68), later w2 (128x64)
    __shared__ float regB[4096];   // w1 (64x64)
    __shared__ float prm[512];

    const int t = threadIdx.x;
    if (t < 64) {
        float a0v = g0[t] / sqrtf(v0[t] + 1e-5f);
        prm[t]       = a0v;
        prm[64 + t]  = b0[t] - m0[t] * a0v;
        float a1v = g1[t] / sqrtf(v1[t] + 1e-5f);
        prm[128 + t] = a1v;
        prm[192 + t] = b1[t] - m1[t] * a1v;
    } else if (t < 192) {
        int o = t - 64;
        float a2v = g2[o] / sqrtf(v2[o] + 1e-5f);
        prm[256 + o] = a2v;
        prm[384 + o] = b2[o] - m2[o] * a2v;
    }
    for (int idx = t; idx < 64 * 68; idx += 256) {
        int o = idx / 68, i = idx - o * 68;
        float v;
        if (i < 64)      v = w0[o * 67 + 3 + i];
        else if (i < 67) v = w0[o * 67 + (i - 64)];
        else             v = 0.0f;
        regA[idx] = v;
    }
    for (int idx = t; idx < 64 * 64; idx += 256) regB[idx] = w1[idx];
    __syncthreads();

    const int gid = blockIdx.x * 256 + t;
    const int sl  = gid >> 5;
    const int s   = sl & (SCENT - 1);
    const int b   = sl >> 11;
    const int nidx = knn_idx[gid];

    const float* q  = new_xyz + (size_t)(b * SCENT + s) * 3;
    const float* P3 = xyz + (size_t)(b * NPTS + nidx) * 3;
    const float dx = P3[0] - q[0], dy = P3[1] - q[1], dz = P3[2] - q[2];

    const float4* F = (const float4*)(ptsT + ((size_t)b * NPTS + nidx) * 64);
    float4 xv[17];
#pragma unroll
    for (int i = 0; i < 16; ++i) xv[i] = F[i];
    xv[16] = make_float4(dx, dy, dz, 0.0f);

    float h0[64];
    const float4* W0 = (const float4*)regA;
#pragma unroll
    for (int o = 0; o < 64; ++o) {
        float acc = 0.f;
#pragma unroll
        for (int i = 0; i < 17; ++i) {
            float4 w = W0[o * 17 + i];
            acc = fmaf(xv[i].x, w.x, acc);
            acc = fmaf(xv[i].y, w.y, acc);
            acc = fmaf(xv[i].z, w.z, acc);
            acc = fmaf(xv[i].w, w.w, acc);
        }
        h0[o] = fmaxf(fmaf(acc, prm[o], prm[64 + o]), 0.f);
    }
    __syncthreads();
    for (int idx = t; idx < 128 * 64; idx += 256) regA[idx] = w2[idx];
    __syncthreads();

    float h1[64];
    const float4* W1 = (const float4*)regB;
#pragma unroll
    for (int o = 0; o < 64; ++o) {
        float acc = 0.f;
#pragma unroll
        for (int i = 0; i < 16; ++i) {
            float4 w = W1[o * 16 + i];
            acc = fmaf(h0[4 * i + 0], w.x, acc);
            acc = fmaf(h0[4 * i + 1], w.y, acc);
            acc = fmaf(h0[4 * i + 2], w.z, acc);
            acc = fmaf(h0[4 * i + 3], w.w, acc);
        }
        h1[o] = fmaxf(fmaf(acc, prm[128 + o], prm[192 + o]), 0.f);
    }

    const float4* W2 = (const float4*)regA;
    float* outp = out_points + (size_t)b * 128 * SCENT + s;
    const int lane = t & 63;
#pragma unroll 1
    for (int o = 0; o < 128; ++o) {
        float acc = 0.f;
#pragma unroll
        for (int i = 0; i < 16; ++i) {
            float4 w = W2[o * 16 + i];
            acc = fmaf(h1[4 * i + 0], w.x, acc);
            acc = fmaf(h1[4 * i + 1], w.y, acc);
            acc = fmaf(h1[4 * i + 2], w.z, acc);
            acc = fmaf(h1[4 * i + 3], w.w, acc);
        }
        float y = fmaxf(fmaf(acc, prm[256 + o], prm[384 + o]), 0.f);
#pragma unroll
        for (int off = 16; off >= 1; off >>= 1) y = fmaxf(y, __shfl_xor(y, off));
        if ((lane & 31) == 0) outp[(size_t)o * SCENT] = y;
    }
}

// ---------------------------------------------------------------------------
extern "C" void kernel_launch(void* const* d_in, const int* in_sizes, int n_in,
                              void* d_out, int out_size, void* d_ws, size_t ws_size,
                              hipStream_t stream) {
    const float* xyz    = (const float*)d_in[0];
    const float* points = (const float*)d_in[1];
    const float* w0 = (const float*)d_in[2];
    const float* g0 = (const float*)d_in[3];
    const float* b0 = (const float*)d_in[4];
    const float* m0 = (const float*)d_in[5];
    const float* v0 = (const float*)d_in[6];
    const float* w1 = (const float*)d_in[7];
    const float* g1 = (const float*)d_in[8];
    const float* b1 = (const float*)d_in[9];
    const float* m1 = (const float*)d_in[10];
    const float* v1 = (const float*)d_in[11];
    const float* w2 = (const float*)d_in[12];
    const float* g2 = (const float*)d_in[13];
    const float* b2 = (const float*)d_in[14];
    const float* m2 = (const float*)d_in[15];
    const float* v2 = (const float*)d_in[16];

    float* out_xyz    = (float*)d_out;                               // (B,S,3)
    float* out_points = (float*)d_out + (size_t)BATCH * SCENT * 3;   // (B,128,S)

    char* ws = (char*)d_ws;
    int*   fps_idx = (int*)ws;                                   // 32 KB
    int*   knn_idx = (int*)(ws + 32768);                         // 1 MB
    float* ptsT    = (float*)(ws + 32768 + (size_t)BATCH * SCENT * KNEIGH * 4); // 8 MB

    fps_kernel<<<BATCH, FPS_T, 0, stream>>>(xyz, out_xyz, fps_idx);
    transpose_kernel<<<dim3(NPTS / 32, DFEAT / 32, BATCH), dim3(32, 8), 0, stream>>>(points, ptsT);
    knn_kernel<<<dim3(SCENT / 4, BATCH), 256, 0, stream>>>(xyz, out_xyz, knn_idx);
    mlp_kernel<<<(BATCH * SCENT * KNEIGH) / 256, 256, 0, stream>>>(
        xyz, out_xyz, ptsT, knn_idx,
        w0, g0, b0, m0, v0, w1, g1, b1, m1, v1, w2, g2, b2, m2, v2, out_points);
}